// Round 1
// baseline (6942.397 us; speedup 1.0000x reference)
//
#include <hip/hip_runtime.h>
#include <stddef.h>

// Problem dims
#define SS 128      // sentence length
#define BB 128      // batch
#define WW 16       // chars per word
#define CEE 64      // char emb / char hidden
#define HH 256      // sentence hidden
#define KT 27       // tagset + START/STOP
// START=25, STOP=26

__device__ __forceinline__ float sigm(float x){ return 1.0f/(1.0f + expf(-x)); }

// ---------------------------------------------------------------------------
// fv[b*S+s][j] = feat_b[j] + sum_f features[b][f][s] * feat_W[j][f]
__global__ __launch_bounds__(256) void k_fv(const float* __restrict__ feat,
                                            const float* __restrict__ fW,
                                            const float* __restrict__ fb,
                                            float* __restrict__ fvb)
{
  int idx = blockIdx.x*256 + threadIdx.x;      // 16384*128 outputs
  int j = idx & 127;
  int r = idx >> 7;
  int b = r >> 7, sw = r & 127;
  const float* x = feat + b*512 + sw;          // stride 128 per feature
  float a = fb[j];
  a = fmaf(x[0],   fW[j*4+0], a);
  a = fmaf(x[128], fW[j*4+1], a);
  a = fmaf(x[256], fW[j*4+2], a);
  a = fmaf(x[384], fW[j*4+3], a);
  fvb[idx] = a;
}

// ---------------------------------------------------------------------------
// One char-LSTM step, both directions. Grid 256 blocks x 256 thr.
// bid: rt = bid&3 (64 gate rows), dir=(bid>>2)&1, chunk=bid>>3 (512 seqs)
// Gate rows unit-major: gi = unit*4 + type; orig row = type*64 + unit.
__global__ __launch_bounds__(256) void k_char_step(
  const int* __restrict__ chars2ix, const float* __restrict__ char_emb,
  const float* __restrict__ Wih_f, const float* __restrict__ Whh_f,
  const float* __restrict__ bih_f, const float* __restrict__ bhh_f,
  const float* __restrict__ Wih_b, const float* __restrict__ Whh_b,
  const float* __restrict__ bih_b, const float* __restrict__ bhh_b,
  const float* __restrict__ hprev, float* __restrict__ hnext,
  float* __restrict__ cstate, int t)
{
  __shared__ __align__(16) float Wc[64*128];   // [gate col][k], swizzled
  __shared__ float bsum[64];
  __shared__ float gbuf[4][64][8];             // wave-local exchange
  int tid = threadIdx.x, bid = blockIdx.x;
  int rt = bid & 3;
  int dir = (bid>>2) & 1;
  int chunk = bid >> 3;
  const float* Wih = dir ? Wih_b : Wih_f;
  const float* Whh = dir ? Whh_b : Whh_f;
  int tpos = dir ? (15 - t) : t;

  for (int i = tid; i < 64*32; i += 256) {
    int l2 = i >> 5, k4 = i & 31;
    int gi = rt*64 + l2, orig = (gi&3)*64 + (gi>>2);
    const float* src = (k4 < 16) ? (Wih + orig*64 + k4*4) : (Whh + orig*64 + (k4-16)*4);
    *(float4*)&Wc[(l2*128 + k4*4) ^ ((l2&7)<<2)] = *(const float4*)src;
  }
  if (tid < 64) {
    int gi = rt*64 + tid, orig = (gi&3)*64 + (gi>>2);
    bsum[tid] = (dir?bih_b:bih_f)[orig] + (dir?bhh_b:bhh_f)[orig];
  }
  __syncthreads();

  int wave = __builtin_amdgcn_readfirstlane((int)(tid >> 6));
  int l = tid & 63;
  const float* hbase = hprev + dir*(16384*64);
  float* hnbase = hnext + dir*(16384*64);
  float* cbase  = cstate + dir*(16384*64);

  for (int it = 0; it < 16; ++it) {
    int seq0 = chunk*512 + it*32 + wave*8;
    float acc[8];
    float bb = bsum[l];
    #pragma unroll
    for (int i=0;i<8;i++) acc[i] = bb;
    const float* xr[8]; const float* hr[8];
    #pragma unroll
    for (int i=0;i<8;i++){
      int seq = seq0 + i;
      xr[i] = char_emb + chars2ix[seq*16 + tpos]*64;
      hr[i] = hbase + seq*64;
    }
    #pragma unroll
    for (int k4=0;k4<16;k4++){
      float4 w = *(const float4*)&Wc[(l*128 + k4*4) ^ ((l&7)<<2)];
      #pragma unroll
      for (int i=0;i<8;i++){
        const float4 x = *(const float4*)(xr[i] + k4*4);
        acc[i] = fmaf(x.x,w.x, fmaf(x.y,w.y, fmaf(x.z,w.z, fmaf(x.w,w.w, acc[i]))));
      }
    }
    #pragma unroll
    for (int k4=0;k4<16;k4++){
      float4 w = *(const float4*)&Wc[(l*128 + 64 + k4*4) ^ ((l&7)<<2)];
      #pragma unroll
      for (int i=0;i<8;i++){
        const float4 x = *(const float4*)(hr[i] + k4*4);
        acc[i] = fmaf(x.x,w.x, fmaf(x.y,w.y, fmaf(x.z,w.z, fmaf(x.w,w.w, acc[i]))));
      }
    }
    // wave-local transpose exchange (no barrier needed: same wave)
    #pragma unroll
    for (int i=0;i<8;i++) gbuf[wave][l][i] = acc[i];
    int ul = l & 15, ss = l >> 4;
    int ug = rt*16 + ul;
    #pragma unroll
    for (int rep=0; rep<2; rep++){
      int s8 = ss + rep*4;
      int seq = seq0 + s8;
      float g_i = gbuf[wave][ul*4+0][s8];
      float g_f = gbuf[wave][ul*4+1][s8];
      float g_g = gbuf[wave][ul*4+2][s8];
      float g_o = gbuf[wave][ul*4+3][s8];
      float c = cbase[seq*64 + ug];
      c = sigm(g_f)*c + sigm(g_i)*tanhf(g_g);
      cbase[seq*64 + ug] = c;
      hnbase[seq*64 + ug] = sigm(g_o)*tanhf(c);
    }
  }
}

// ---------------------------------------------------------------------------
// chvec[r][j] = b2[j] + sum_k<64 hf[r][k]*W2[j][k] + sum_k<64 hb[r][k]*W2[j][64+k]
__global__ __launch_bounds__(256) void k_chvec(
  const float* __restrict__ chh,   // [2][16384][64], dir0=fwd final, dir1=bwd final
  const float* __restrict__ W2, const float* __restrict__ b2,
  float* __restrict__ chvec)
{
  __shared__ __align__(16) float Wc[64*128];
  __shared__ __align__(16) float gout[4][8][64];
  int tid = threadIdx.x, bid = blockIdx.x;
  for (int i=tid;i<64*32;i+=256){
    int l2=i>>5, k4=i&31;
    *(float4*)&Wc[(l2*128 + k4*4) ^ ((l2&7)<<2)] = *(const float4*)(W2 + l2*128 + k4*4);
  }
  __syncthreads();
  int wave = __builtin_amdgcn_readfirstlane((int)(tid>>6));
  int l = tid & 63;
  float bb = b2[l];
  for (int it=0; it<2; ++it){
    int r0 = bid*64 + it*32 + wave*8;
    float acc[8];
    #pragma unroll
    for (int i=0;i<8;i++) acc[i]=bb;
    const float* hf[8]; const float* hb[8];
    #pragma unroll
    for (int i=0;i<8;i++){ hf[i]=chh+(size_t)(r0+i)*64; hb[i]=chh+(size_t)(16384+r0+i)*64; }
    #pragma unroll
    for (int k4=0;k4<16;k4++){
      float4 w=*(const float4*)&Wc[(l*128+k4*4)^((l&7)<<2)];
      #pragma unroll
      for (int i=0;i<8;i++){
        const float4 x=*(const float4*)(hf[i]+k4*4);
        acc[i]=fmaf(x.x,w.x,fmaf(x.y,w.y,fmaf(x.z,w.z,fmaf(x.w,w.w,acc[i]))));
      }
    }
    #pragma unroll
    for (int k4=0;k4<16;k4++){
      float4 w=*(const float4*)&Wc[(l*128+64+k4*4)^((l&7)<<2)];
      #pragma unroll
      for (int i=0;i<8;i++){
        const float4 x=*(const float4*)(hb[i]+k4*4);
        acc[i]=fmaf(x.x,w.x,fmaf(x.y,w.y,fmaf(x.z,w.z,fmaf(x.w,w.w,acc[i]))));
      }
    }
    #pragma unroll
    for (int i=0;i<8;i++) gout[wave][i][l]=acc[i];
    int rsub=l>>3, cg=l&7;
    #pragma unroll
    for (int i2=0;i2<2;i2++){
      int col=cg*8+i2*4;
      *(float4*)&chvec[(size_t)(r0+rsub)*64+col] = *(const float4*)&gout[wave][rsub][col];
    }
  }
}

// ---------------------------------------------------------------------------
// gx[dir][s*128+b][gi] (unit-major) += vec-segment @ Wih^T  (SEG 0 inits w/ biases)
// SEG 0: word_emb (K=128), SEG 1: chvec (K=64), SEG 2: fv (K=128)
template<int SEG>
__global__ __launch_bounds__(256) void k_gx_seg(
  const int* __restrict__ words2ix, const float* __restrict__ word_emb,
  const float* __restrict__ chvec, const float* __restrict__ fvb,
  const float* __restrict__ Wih_f, const float* __restrict__ bih_f, const float* __restrict__ bhh_f,
  const float* __restrict__ Wih_b, const float* __restrict__ bih_b, const float* __restrict__ bhh_b,
  float* __restrict__ gxf, float* __restrict__ gxb)
{
  constexpr int KS   = (SEG==1) ? 64 : 128;
  constexpr int KOFF = (SEG==0) ? 0 : (SEG==1) ? 128 : 192;
  __shared__ __align__(16) float Wg[64*KS];
  __shared__ float bsum[64];
  __shared__ __align__(16) float gout[4][8][64];
  int tid=threadIdx.x, bid=blockIdx.x;
  int ct = bid & 15, dir = (bid>>4)&1, rch = bid>>5;
  const float* Wih = dir ? Wih_b : Wih_f;
  float* gx = dir ? gxb : gxf;
  for (int i=tid; i<64*(KS/4); i+=256){
    int l2 = i/(KS/4), k4 = i%(KS/4);
    int gi = ct*64 + l2, orig = (gi&3)*256 + (gi>>2);
    *(float4*)&Wg[(l2*KS + k4*4) ^ ((l2&7)<<2)] = *(const float4*)(Wih + orig*320 + KOFF + k4*4);
  }
  if (SEG==0 && tid<64){
    int gi = ct*64 + tid, orig = (gi&3)*256 + (gi>>2);
    bsum[tid] = (dir?bih_b:bih_f)[orig] + (dir?bhh_b:bhh_f)[orig];
  }
  __syncthreads();
  int wave = __builtin_amdgcn_readfirstlane((int)(tid>>6));
  int l = tid & 63;
  for (int it=0; it<64; ++it){
    int r0 = rch*2048 + it*32 + wave*8;
    float acc[8];
    if (SEG==0){ float bb=bsum[l];
      #pragma unroll
      for(int i=0;i<8;i++) acc[i]=bb;
    } else {
      #pragma unroll
      for(int i=0;i<8;i++) acc[i]=0.f;
    }
    const float* rp[8];
    #pragma unroll
    for (int i=0;i<8;i++){
      int r=r0+i; int b=r&127, sw=r>>7; int rid=b*128+sw;
      rp[i] = (SEG==0) ? (word_emb + words2ix[rid]*128)
            : (SEG==1) ? (chvec + (size_t)rid*64)
                       : (fvb + (size_t)rid*128);
    }
    #pragma unroll
    for (int k4=0;k4<KS/4;k4++){
      float4 w=*(const float4*)&Wg[(l*KS + k4*4) ^ ((l&7)<<2)];
      #pragma unroll
      for (int i=0;i<8;i++){
        const float4 x=*(const float4*)(rp[i]+k4*4);
        acc[i]=fmaf(x.x,w.x,fmaf(x.y,w.y,fmaf(x.z,w.z,fmaf(x.w,w.w,acc[i]))));
      }
    }
    #pragma unroll
    for (int i=0;i<8;i++) gout[wave][i][l]=acc[i];
    int rsub=l>>3, cg=l&7;
    #pragma unroll
    for (int i2=0;i2<2;i2++){
      int col=cg*8+i2*4;
      float4 v=*(const float4*)&gout[wave][rsub][col];
      float* dst=&gx[(size_t)(r0+rsub)*1024 + ct*64 + col];
      if (SEG==0) *(float4*)dst = v;
      else { float4 o=*(const float4*)dst; o.x+=v.x;o.y+=v.y;o.z+=v.z;o.w+=v.w; *(float4*)dst=o; }
    }
  }
}

// ---------------------------------------------------------------------------
// One sentence-LSTM step, both dirs. Grid 256: rt=bid&15 (64 gate rows),
// dir=(bid>>4)&1, bch=bid>>5 (16 b). K=256 in two staged passes of 128.
__global__ __launch_bounds__(256) void k_sent_step(
  const float* __restrict__ gxf, const float* __restrict__ gxb,
  const float* __restrict__ Whh_f, const float* __restrict__ Whh_b,
  const float* __restrict__ hprev, float* __restrict__ hnext,
  float* __restrict__ cstate, float* __restrict__ hsf, float* __restrict__ hsb, int s)
{
  __shared__ __align__(16) float Ws[64*128];
  __shared__ float gbuf[4][64][4];
  int tid=threadIdx.x, bid=blockIdx.x;
  int rt=bid&15, dir=(bid>>4)&1, bch=bid>>5;
  int spos = dir ? (127 - s) : s;
  const float* Whh = dir ? Whh_b : Whh_f;
  const float* gx  = dir ? gxb : gxf;
  int wave = __builtin_amdgcn_readfirstlane((int)(tid>>6));
  int l = tid & 63;
  int b0 = bch*16 + wave*4;
  float acc[4];
  #pragma unroll
  for (int i=0;i<4;i++) acc[i] = gx[(size_t)(spos*128 + b0 + i)*1024 + rt*64 + l];
  const float* hr[4];
  #pragma unroll
  for (int i=0;i<4;i++) hr[i] = hprev + (size_t)(dir*128 + b0 + i)*256;

  for (int i=tid;i<64*32;i+=256){
    int l2=i>>5,k4=i&31; int gi=rt*64+l2, orig=(gi&3)*256+(gi>>2);
    *(float4*)&Ws[(l2*128+k4*4)^((l2&7)<<2)] = *(const float4*)(Whh + orig*256 + k4*4);
  }
  __syncthreads();
  #pragma unroll
  for (int k4=0;k4<32;k4++){
    float4 w=*(const float4*)&Ws[(l*128+k4*4)^((l&7)<<2)];
    #pragma unroll
    for (int i=0;i<4;i++){
      const float4 x=*(const float4*)(hr[i]+k4*4);
      acc[i]=fmaf(x.x,w.x,fmaf(x.y,w.y,fmaf(x.z,w.z,fmaf(x.w,w.w,acc[i]))));
    }
  }
  __syncthreads();
  for (int i=tid;i<64*32;i+=256){
    int l2=i>>5,k4=i&31; int gi=rt*64+l2, orig=(gi&3)*256+(gi>>2);
    *(float4*)&Ws[(l2*128+k4*4)^((l2&7)<<2)] = *(const float4*)(Whh + orig*256 + 128 + k4*4);
  }
  __syncthreads();
  #pragma unroll
  for (int k4=0;k4<32;k4++){
    float4 w=*(const float4*)&Ws[(l*128+k4*4)^((l&7)<<2)];
    #pragma unroll
    for (int i=0;i<4;i++){
      const float4 x=*(const float4*)(hr[i]+128+k4*4);
      acc[i]=fmaf(x.x,w.x,fmaf(x.y,w.y,fmaf(x.z,w.z,fmaf(x.w,w.w,acc[i]))));
    }
  }
  // wave-local exchange
  #pragma unroll
  for (int i=0;i<4;i++) gbuf[wave][l][i]=acc[i];
  int ul=l&15, bs=l>>4;
  int b = bch*16 + wave*4 + bs;
  int ug = rt*16 + ul;
  float g_i=gbuf[wave][ul*4+0][bs], g_f=gbuf[wave][ul*4+1][bs];
  float g_g=gbuf[wave][ul*4+2][bs], g_o=gbuf[wave][ul*4+3][bs];
  float* cp = cstate + (size_t)(dir*128 + b)*256 + ug;
  float c = *cp;
  c = sigm(g_f)*c + sigm(g_i)*tanhf(g_g);
  *cp = c;
  float h = sigm(g_o)*tanhf(c);
  hnext[(size_t)(dir*128 + b)*256 + ug] = h;
  (dir ? hsb : hsf)[(size_t)(spos*128 + b)*256 + ug] = h;
}

// ---------------------------------------------------------------------------
// feats[b*128+s][k] = tag_b[k] + [hsf|hsb|chvec|fv] . tag_W[k]  (K=704, 2 passes)
__global__ __launch_bounds__(256) void k_feats(
  const float* __restrict__ hsf, const float* __restrict__ hsb,
  const float* __restrict__ chvec, const float* __restrict__ fvb,
  const float* __restrict__ tagW, const float* __restrict__ tagb,
  float* __restrict__ feats)
{
  __shared__ __align__(16) float Wt[27*352];
  int tid=threadIdx.x, bid=blockIdx.x;
  int wave=__builtin_amdgcn_readfirstlane((int)(tid>>6));
  int l=tid&63;
  int r0=bid*32+wave*8;
  bool act = (l < 27);
  float acc[8];
  #pragma unroll
  for (int i=0;i<8;i++) acc[i] = act ? tagb[l] : 0.f;
  const float* hfr[8]; const float* hbr[8]; const float* cr[8]; const float* fr[8];
  #pragma unroll
  for (int i=0;i<8;i++){
    int r=r0+i; int b=r>>7, sw=r&127;
    hfr[i]=hsf + (size_t)(sw*128+b)*256;
    hbr[i]=hsb + (size_t)(sw*128+b)*256;
    cr[i]=chvec + (size_t)r*64;
    fr[i]=fvb + (size_t)r*128;
  }
  // pass 0: global k 0..351
  for (int i=tid;i<27*88;i+=256){
    int rr=i/88, k4=i%88;
    *(float4*)&Wt[(rr*352+k4*4)^((rr&7)<<2)] = *(const float4*)(tagW + rr*704 + k4*4);
  }
  __syncthreads();
  if (act){
    for (int k4=0;k4<64;k4++){
      float4 w=*(const float4*)&Wt[(l*352+k4*4)^((l&7)<<2)];
      #pragma unroll
      for (int i=0;i<8;i++){
        const float4 x=*(const float4*)(hfr[i]+k4*4);
        acc[i]=fmaf(x.x,w.x,fmaf(x.y,w.y,fmaf(x.z,w.z,fmaf(x.w,w.w,acc[i]))));
      }
    }
    for (int k4=64;k4<88;k4++){
      float4 w=*(const float4*)&Wt[(l*352+k4*4)^((l&7)<<2)];
      #pragma unroll
      for (int i=0;i<8;i++){
        const float4 x=*(const float4*)(hbr[i]+(k4-64)*4);
        acc[i]=fmaf(x.x,w.x,fmaf(x.y,w.y,fmaf(x.z,w.z,fmaf(x.w,w.w,acc[i]))));
      }
    }
  }
  __syncthreads();
  // pass 1: global k 352..703
  for (int i=tid;i<27*88;i+=256){
    int rr=i/88, k4=i%88;
    *(float4*)&Wt[(rr*352+k4*4)^((rr&7)<<2)] = *(const float4*)(tagW + rr*704 + 352 + k4*4);
  }
  __syncthreads();
  if (act){
    for (int k4=0;k4<40;k4++){
      float4 w=*(const float4*)&Wt[(l*352+k4*4)^((l&7)<<2)];
      #pragma unroll
      for (int i=0;i<8;i++){
        const float4 x=*(const float4*)(hbr[i]+96+k4*4);
        acc[i]=fmaf(x.x,w.x,fmaf(x.y,w.y,fmaf(x.z,w.z,fmaf(x.w,w.w,acc[i]))));
      }
    }
    for (int k4=40;k4<56;k4++){
      float4 w=*(const float4*)&Wt[(l*352+k4*4)^((l&7)<<2)];
      #pragma unroll
      for (int i=0;i<8;i++){
        const float4 x=*(const float4*)(cr[i]+(k4-40)*4);
        acc[i]=fmaf(x.x,w.x,fmaf(x.y,w.y,fmaf(x.z,w.z,fmaf(x.w,w.w,acc[i]))));
      }
    }
    for (int k4=56;k4<88;k4++){
      float4 w=*(const float4*)&Wt[(l*352+k4*4)^((l&7)<<2)];
      #pragma unroll
      for (int i=0;i<8;i++){
        const float4 x=*(const float4*)(fr[i]+(k4-56)*4);
        acc[i]=fmaf(x.x,w.x,fmaf(x.y,w.y,fmaf(x.z,w.z,fmaf(x.w,w.w,acc[i]))));
      }
    }
    #pragma unroll
    for (int i=0;i<8;i++) feats[(size_t)(r0+i)*27 + l] = acc[i];
  }
}

// ---------------------------------------------------------------------------
__global__ __launch_bounds__(256) void k_argmax(const float* __restrict__ feats,
                                                float* __restrict__ out)
{
  int r = blockIdx.x*256 + threadIdx.x;   // 16384
  const float* f = feats + (size_t)r*27;
  float best = f[0]; int bi = 0;
  #pragma unroll
  for (int j=1;j<27;j++){ float v=f[j]; if (v>best){best=v;bi=j;} }
  out[r] = (float)bi;
}

// ---------------------------------------------------------------------------
// Viterbi: one wave per batch row.
__global__ __launch_bounds__(64) void k_viterbi(
  const float* __restrict__ feats, const int* __restrict__ mask,
  const float* __restrict__ trans, float* __restrict__ out)
{
  __shared__ float tr[729];
  __shared__ unsigned char bp[127][27];
  __shared__ int tags[128];
  int b = blockIdx.x, l = threadIdx.x;
  for (int i=l;i<729;i+=64) tr[i]=trans[i];
  __syncthreads();
  int ll = (l<27) ? l : 0;
  float trc[27];
  #pragma unroll
  for (int i=0;i<27;i++) trc[i]=tr[i*27+ll];
  const float* fb_ = feats + (size_t)b*128*27;
  float score = fb_[ll] + tr[25*27 + ll];
  for (int t=1;t<128;t++){
    float best=-3.0e38f; int bi=0;
    #pragma unroll 1
    for (int i=0;i<27;i++){
      float si = __shfl(score, i, 64);
      float cand = si + trc[i];
      if (cand > best){ best=cand; bi=i; }
    }
    int m = mask[b*128 + t];
    float ns = best + fb_[t*27 + ll];
    if (m) score = ns;
    int bpv = m ? bi : ll;
    if (l < 27) bp[t-1][l] = (unsigned char)bpv;
  }
  float fin = score + tr[ll*27 + 26];
  if (l >= 27) fin = -3.0e38f;
  float bestf=-3.0e38f; int bt=0;
  #pragma unroll 1
  for (int i=0;i<27;i++){
    float v=__shfl(fin, i, 64);
    if (v > bestf){ bestf=v; bt=i; }
  }
  if (l==0){
    out[b]=bestf;
    int tg=bt; tags[127]=tg;
    for (int t=126;t>=0;t--){ tg = bp[t][tg]; tags[t]=tg; }
  }
  __syncthreads();
  float* op = out + 128 + b*128;
  for (int t=l;t<128;t+=64) op[t]=(float)tags[t];
}

// ---------------------------------------------------------------------------
extern "C" void kernel_launch(void* const* d_in, const int* in_sizes, int n_in,
                              void* d_out, int out_size, void* d_ws, size_t ws_size,
                              hipStream_t stream)
{
  (void)in_sizes; (void)n_in; (void)out_size; (void)ws_size;
  const int*   words2ix = (const int*)d_in[0];
  const int*   chars2ix = (const int*)d_in[1];
  const float* features = (const float*)d_in[2];
  const int*   amask    = (const int*)d_in[3];
  const float* word_emb = (const float*)d_in[4];
  const float* char_emb = (const float*)d_in[5];
  const float* cWih_f=(const float*)d_in[6],  *cWhh_f=(const float*)d_in[7];
  const float* cbih_f=(const float*)d_in[8],  *cbhh_f=(const float*)d_in[9];
  const float* cWih_b=(const float*)d_in[10], *cWhh_b=(const float*)d_in[11];
  const float* cbih_b=(const float*)d_in[12], *cbhh_b=(const float*)d_in[13];
  const float* coW=(const float*)d_in[14], *cob=(const float*)d_in[15];
  const float* fW =(const float*)d_in[16], *fb =(const float*)d_in[17];
  const float* lWih_f=(const float*)d_in[18], *lWhh_f=(const float*)d_in[19];
  const float* lbih_f=(const float*)d_in[20], *lbhh_f=(const float*)d_in[21];
  const float* lWih_b=(const float*)d_in[22], *lWhh_b=(const float*)d_in[23];
  const float* lbih_b=(const float*)d_in[24], *lbhh_b=(const float*)d_in[25];
  const float* tagW=(const float*)d_in[26], *tagb=(const float*)d_in[27];
  const float* trans=(const float*)d_in[28];
  float* out = (float*)d_out;

  float* p = (float*)d_ws;
  float* chvec = p; p += 16384*64;
  float* fvb   = p; p += 16384*128;
  float* gxf   = p; p += (size_t)16384*1024;
  float* gxb   = p; p += (size_t)16384*1024;
  float* chhA  = p; p += 2*16384*64;
  float* chhB  = p; p += 2*16384*64;
  float* chc   = p; p += 2*16384*64;
  float* shA   = p; p += 2*128*256;
  float* shB   = p; p += 2*128*256;
  float* ssc   = p; p += 2*128*256;
  float* hsf   = p; p += (size_t)128*128*256;
  float* hsb   = p; p += (size_t)128*128*256;
  float* feats = p; p += 16384*27;

  hipMemsetAsync(chhA, 0, (size_t)2*16384*64*sizeof(float), stream);
  hipMemsetAsync(chc , 0, (size_t)2*16384*64*sizeof(float), stream);
  hipMemsetAsync(shA , 0, (size_t)2*128*256*sizeof(float), stream);
  hipMemsetAsync(ssc , 0, (size_t)2*128*256*sizeof(float), stream);

  k_fv<<<8192,256,0,stream>>>(features, fW, fb, fvb);

  for (int t=0;t<16;t++){
    const float* hp = (t&1) ? chhB : chhA;
    float* hn = (t&1) ? chhA : chhB;
    k_char_step<<<256,256,0,stream>>>(chars2ix, char_emb,
      cWih_f,cWhh_f,cbih_f,cbhh_f, cWih_b,cWhh_b,cbih_b,cbhh_b,
      hp, hn, chc, t);
  }
  k_chvec<<<256,256,0,stream>>>(chhA, coW, cob, chvec);

  k_gx_seg<0><<<256,256,0,stream>>>(words2ix, word_emb, chvec, fvb,
      lWih_f,lbih_f,lbhh_f, lWih_b,lbih_b,lbhh_b, gxf, gxb);
  k_gx_seg<1><<<256,256,0,stream>>>(words2ix, word_emb, chvec, fvb,
      lWih_f,lbih_f,lbhh_f, lWih_b,lbih_b,lbhh_b, gxf, gxb);
  k_gx_seg<2><<<256,256,0,stream>>>(words2ix, word_emb, chvec, fvb,
      lWih_f,lbih_f,lbhh_f, lWih_b,lbih_b,lbhh_b, gxf, gxb);

  for (int s=0;s<128;s++){
    const float* hp = (s&1) ? shB : shA;
    float* hn = (s&1) ? shA : shB;
    k_sent_step<<<256,256,0,stream>>>(gxf, gxb, lWhh_f, lWhh_b,
      hp, hn, ssc, hsf, hsb, s);
  }

  k_feats<<<512,256,0,stream>>>(hsf, hsb, chvec, fvb, tagW, tagb, feats);
  k_argmax<<<64,256,0,stream>>>(feats, out + 128 + 16384);
  k_viterbi<<<128,64,0,stream>>>(feats, amask, trans, out);
}